// Round 10
// baseline (323.670 us; speedup 1.0000x reference)
//
#include <hip/hip_runtime.h>

#define LRELU(x) ((x) > 0.f ? (x) : 0.01f * (x))

// ws layout (float offsets)
#define H2_OFF    0          // [8][16][512]
#define T1_OFF    65536      // [8][512]
#define T2_OFF    69632      // [8][512]
#define PK_OFF    73728      // [8][2048]
#define PB_OFF    90112      // [8][512]
#define D_OFF     94208      // [8][9][2048]
#define WB_OFF    241664     // [8][128][160]  (144 weff + 4 pb + 12 pad)

// ---------------- kA: h (1x1 conv + lrelu), pooled stage 1, and D zero-init ----------------
__global__ __launch_bounds__(256) void kA(const float* __restrict__ style,
    const float* __restrict__ dw1_w, const float* __restrict__ dw1_b,
    const float* __restrict__ pk1_w, const float* __restrict__ pk1_b,
    const float* __restrict__ pb1_w, const float* __restrict__ pb1_b,
    float* __restrict__ h2, float* __restrict__ t1, float* __restrict__ t2,
    float* __restrict__ D) {
  int b = blockIdx.x;
  __shared__ float s[512];
  if (b >= 272) {
    // zero D: 8*9*2048 floats = 36864 float4, 16384 threads
    int idx = (b - 272) * 256 + threadIdx.x;
    float4 z; z.x = 0.f; z.y = 0.f; z.z = 0.f; z.w = 0.f;
    for (int j = idx; j < 36864; j += 16384) ((float4*)D)[j] = z;
    return;
  }
  if (b < 256) {
    int n = b >> 5, pix = (b >> 1) & 15, half = b & 1;
    const float* sp = style + n * 8192 + pix;
    for (int i = threadIdx.x; i < 512; i += 256) s[i] = sp[i * 16];
    __syncthreads();
    int co = half * 256 + threadIdx.x;
    const float4* wr = (const float4*)(dw1_w + co * 512);
    float acc = dw1_b[co];
#pragma unroll 8
    for (int k = 0; k < 128; ++k) {
      float4 wv = wr[k];
      acc += wv.x * s[4*k] + wv.y * s[4*k+1] + wv.z * s[4*k+2] + wv.w * s[4*k+3];
    }
    h2[n * 8192 + pix * 512 + co] = LRELU(acc);
  } else {
    int idx = b - 256; int n = idx >> 1, which = idx & 1;
    for (int ci = threadIdx.x; ci < 512; ci += 256) {
      const float4* r4 = (const float4*)(style + n * 8192 + ci * 16);
      float4 a = r4[0], bb = r4[1], c = r4[2], d = r4[3];
      s[ci] = (a.x+a.y+a.z+a.w + bb.x+bb.y+bb.z+bb.w + c.x+c.y+c.z+c.w + d.x+d.y+d.z+d.w) * (1.f/16.f);
    }
    __syncthreads();
    const float* w  = which ? pb1_w : pk1_w;
    const float* bv = which ? pb1_b : pk1_b;
    float* o = which ? t2 : t1;
    for (int co = threadIdx.x; co < 512; co += 256) {
      const float4* wr = (const float4*)(w + co * 512);
      float acc = bv[co];
#pragma unroll 8
      for (int k = 0; k < 128; ++k) {
        float4 wv = wr[k];
        acc += wv.x * s[4*k] + wv.y * s[4*k+1] + wv.z * s[4*k+2] + wv.w * s[4*k+3];
      }
      o[n * 512 + co] = LRELU(acc);
    }
  }
}

// ---------------- kB: dw2 matmul (on-the-fly im2col) + pk2/pb2 ----------------
__global__ __launch_bounds__(256) void kB(const float* __restrict__ h2,
    const float* __restrict__ dw2_w,
    const float* __restrict__ t1, const float* __restrict__ t2,
    const float* __restrict__ pk2_w, const float* __restrict__ pk2_b,
    const float* __restrict__ pb2_w, const float* __restrict__ pb2_b,
    float* __restrict__ D, float* __restrict__ pk, float* __restrict__ pb) {
  __shared__ float smem[1280];
  int b = blockIdx.x;
  int tid = threadIdx.x;
  if (b < 512) {
    int kc = b & 31; int bt = b >> 5; int bo = bt & 7; int nh = bt >> 3;
    {
      int pix = tid & 15; int ci4 = (tid >> 4) & 3; int nn = tid >> 6;
      const float* src = h2 + (nh * 4 + nn) * 8192 + pix * 512 + kc * 16 + ci4 * 4;
      float4 v = *(const float4*)src;
      float* dst = &smem[(nn * 16 + ci4 * 4) * 20 + pix];
      dst[0]  = v.x;
      dst[20] = v.y;
      dst[40] = v.z;
      dst[60] = v.w;
    }
    __syncthreads();
    int o2 = bo * 256 + tid;
    const float4* wr = (const float4*)(dw2_w + o2 * 2048 + kc * 64);
    float acc[4][9];
#pragma unroll
    for (int nn = 0; nn < 4; ++nn)
#pragma unroll
      for (int p = 0; p < 9; ++p) acc[nn][p] = 0.f;
    for (int ci = 0; ci < 16; ++ci) {
      float4 wv = wr[ci];
#pragma unroll
      for (int nn = 0; nn < 4; ++nn) {
        const float* hrow = &smem[(nn * 16 + ci) * 20];
        float4 a0 = *(const float4*)(hrow + 0);
        float4 a1 = *(const float4*)(hrow + 4);
        float4 a2 = *(const float4*)(hrow + 8);
        float4 a3 = *(const float4*)(hrow + 12);
        float vv[16];
        vv[0]=a0.x; vv[1]=a0.y; vv[2]=a0.z; vv[3]=a0.w;
        vv[4]=a1.x; vv[5]=a1.y; vv[6]=a1.z; vv[7]=a1.w;
        vv[8]=a2.x; vv[9]=a2.y; vv[10]=a2.z; vv[11]=a2.w;
        vv[12]=a3.x; vv[13]=a3.y; vv[14]=a3.z; vv[15]=a3.w;
#pragma unroll
        for (int p = 0; p < 9; ++p) {
          int r = (p / 3) * 4 + (p % 3);
          acc[nn][p] += wv.x * vv[r] + wv.y * vv[r + 1] + wv.z * vv[r + 4] + wv.w * vv[r + 5];
        }
      }
    }
#pragma unroll
    for (int nn = 0; nn < 4; ++nn)
#pragma unroll
      for (int p = 0; p < 9; ++p)
        atomicAdd(&D[((nh * 4 + nn) * 9 + p) * 2048 + o2], acc[nn][p]);
  } else {
    int idx = b - 512;
    int n = idx / 10; int tile = idx % 10;
    bool isPb = tile >= 8;
    float* s = smem;
    const float* src = (isPb ? t2 : t1) + n * 512;
    for (int i = tid; i < 512; i += 256) s[i] = src[i];
    __syncthreads();
    int o = (isPb ? tile - 8 : tile) * 256 + tid;
    const float* w = isPb ? pb2_w : pk2_w;
    float acc = (isPb ? pb2_b : pk2_b)[o];
    const float4* wr = (const float4*)(w + o * 512);
#pragma unroll 8
    for (int k = 0; k < 128; ++k) {
      float4 wv = wr[k];
      acc += wv.x * s[4*k] + wv.y * s[4*k+1] + wv.z * s[4*k+2] + wv.w * s[4*k+3];
    }
    if (isPb) pb[n * 512 + o] = acc; else pk[n * 2048 + o] = acc;
  }
}

// ---------------- kW: weff + pb -> wbuf[n][Q][160] ----------------
__global__ __launch_bounds__(256) void kW(const float* __restrict__ D,
    const float* __restrict__ pk, const float* __restrict__ dw2_b,
    const float* __restrict__ pb, float* __restrict__ wbuf) {
  int idx = blockIdx.x * 256 + threadIdx.x;
  if (idx >= 8 * 128 * 160) return;
  int t = idx % 160; int Qn = idx / 160; int Q = Qn & 127; int n = Qn >> 7;
  if (t >= 144) {
    wbuf[idx] = (t < 148) ? pb[n * 512 + Q * 4 + (t - 144)] : 0.f;
    return;
  }
  int o = t & 3; int u = t >> 2; int kx = u % 3; int v = u / 3;
  int i = v & 3; int ky = v >> 2; int p = ky * 3 + kx;
  const float* Dp  = D + (n * 9 + p) * 2048 + 16 * Q;
  const float* pkp = pk + n * 2048 + 16 * Q + 4 * o;
  const float* bp  = dw2_b + 16 * Q;
  float sum = 0.f;
#pragma unroll
  for (int j = 0; j < 4; ++j) sum += pkp[j] * (Dp[4 * j + i] + bp[4 * j + i]);
  wbuf[idx] = sum;
}

// ---------------- kC v7: no-LDS, per-row windows, shfl halos, VGPR<=64 ----------------
// block = (n, Q, 32-row half); thread = (y row, e 8-px segment): 4 o x 8 px
__global__ __launch_bounds__(256, 8) void kC(const float* __restrict__ x,
    const float* __restrict__ wbuf, float* __restrict__ out) {
  int b = blockIdx.x; int half = b & 1; int Q = (b >> 1) & 127; int n = b >> 8;
  const float* wb = wbuf + (size_t)(n * 128 + Q) * 160;  // block-uniform -> s_load
  const float* base = x + (size_t)(n * 512 + Q * 4) * 4096;
  int e = threadIdx.x & 7;
  int y = half * 32 + (threadIdx.x >> 3);
  int x0 = 8 * e;
  int ro[3];
#pragma unroll
  for (int ky = 0; ky < 3; ++ky) {
    int ry = y - 1 + ky;
    ry = ry < 0 ? 1 : (ry > 63 ? 62 : ry);
    ro[ky] = ry * 64;
  }
  float acc[4][8];
#pragma unroll
  for (int o = 0; o < 4; ++o) {
    float bv = wb[144 + o];
#pragma unroll
    for (int px = 0; px < 8; ++px) acc[o][px] = bv;
  }
#pragma unroll
  for (int i = 0; i < 4; ++i) {
    const float* ci = base + i * 4096;
#pragma unroll
    for (int ky = 0; ky < 3; ++ky) {
      const float* rp = ci + ro[ky];
      float4 v0 = *(const float4*)(rp + x0);
      float4 v1 = *(const float4*)(rp + x0 + 4);
      // halos via intra-wave shuffle within 8-lane (same-y) groups
      float vl = __shfl_up(v1.w, 1, 8);    // lane e-1's x0+7 = x0-1
      float vr = __shfl_down(v0.x, 1, 8);  // lane e+1's x0+8
      if (e == 0) vl = v0.y;               // x=-1 -> reflect x=1
      if (e == 7) vr = v1.z;               // x=64 -> reflect x=62
      float va[10];
      va[0] = vl;
      va[1] = v0.x; va[2] = v0.y; va[3] = v0.z; va[4] = v0.w;
      va[5] = v1.x; va[6] = v1.y; va[7] = v1.z; va[8] = v1.w;
      va[9] = vr;
#pragma unroll
      for (int kx = 0; kx < 3; ++kx) {
        const float* wp = &wb[((ky * 4 + i) * 3 + kx) * 4];
        float w0 = wp[0], w1 = wp[1], w2 = wp[2], w3 = wp[3];
#pragma unroll
        for (int px = 0; px < 8; ++px) {
          float xv = va[px + kx];
          acc[0][px] += w0 * xv;
          acc[1][px] += w1 * xv;
          acc[2][px] += w2 * xv;
          acc[3][px] += w3 * xv;
        }
      }
    }
  }
#pragma unroll
  for (int o = 0; o < 4; ++o) {
    float* op = out + (((size_t)(n * 512 + Q * 4 + o)) * 64 + y) * 64 + x0;
    float4 s0; s0.x = acc[o][0]; s0.y = acc[o][1]; s0.z = acc[o][2]; s0.w = acc[o][3];
    float4 s1; s1.x = acc[o][4]; s1.y = acc[o][5]; s1.z = acc[o][6]; s1.w = acc[o][7];
    *(float4*)op = s0;
    *(float4*)(op + 4) = s1;
  }
}

extern "C" void kernel_launch(void* const* d_in, const int* in_sizes, int n_in,
                              void* d_out, int out_size, void* d_ws, size_t ws_size,
                              hipStream_t stream) {
  const float* style = (const float*)d_in[0];
  const float* pred  = (const float*)d_in[1];
  const float* dw1_w = (const float*)d_in[2];
  const float* dw1_b = (const float*)d_in[3];
  const float* dw2_w = (const float*)d_in[4];
  const float* dw2_b = (const float*)d_in[5];
  const float* pk1_w = (const float*)d_in[6];
  const float* pk1_b = (const float*)d_in[7];
  const float* pk2_w = (const float*)d_in[8];
  const float* pk2_b = (const float*)d_in[9];
  const float* pb1_w = (const float*)d_in[10];
  const float* pb1_b = (const float*)d_in[11];
  const float* pb2_w = (const float*)d_in[12];
  const float* pb2_b = (const float*)d_in[13];
  float* ws = (float*)d_ws;
  float* h2 = ws + H2_OFF;
  float* t1 = ws + T1_OFF;
  float* t2 = ws + T2_OFF;
  float* pk = ws + PK_OFF;
  float* pb = ws + PB_OFF;
  float* D  = ws + D_OFF;
  float* wb = ws + WB_OFF;
  float* out = (float*)d_out;

  kA<<<336, 256, 0, stream>>>(style, dw1_w, dw1_b, pk1_w, pk1_b, pb1_w, pb1_b, h2, t1, t2, D);
  kB<<<592, 256, 0, stream>>>(h2, dw2_w, t1, t2, pk2_w, pk2_b, pb2_w, pb2_b, D, pk, pb);
  kW<<<640, 256, 0, stream>>>(D, pk, dw2_b, pb, wb);
  kC<<<2048, 256, 0, stream>>>(pred, wb, out);
}

// Round 12
// 190.059 us; speedup vs baseline: 1.7030x; 1.7030x over previous
//
#include <hip/hip_runtime.h>

#define LRELU(x) ((x) > 0.f ? (x) : 0.01f * (x))

// ws layout (float offsets)
#define H2_OFF    0          // [8][16][512]
#define T1_OFF    65536      // [8][512]
#define T2_OFF    69632      // [8][512]
#define PK_OFF    73728      // [8][2048]
#define PB_OFF    90112      // [8][512]
#define D_OFF     94208      // [8][9][2048]
#define WB_OFF    241664     // [8][128][160]  (144 weff + 4 pb + 12 pad)

// ---------------- kA: h (1x1 conv + lrelu), pooled stage 1, and D zero-init ----------------
__global__ __launch_bounds__(256) void kA(const float* __restrict__ style,
    const float* __restrict__ dw1_w, const float* __restrict__ dw1_b,
    const float* __restrict__ pk1_w, const float* __restrict__ pk1_b,
    const float* __restrict__ pb1_w, const float* __restrict__ pb1_b,
    float* __restrict__ h2, float* __restrict__ t1, float* __restrict__ t2,
    float* __restrict__ D) {
  int b = blockIdx.x;
  __shared__ float s[512];
  if (b >= 272) {
    int idx = (b - 272) * 256 + threadIdx.x;
    float4 z; z.x = 0.f; z.y = 0.f; z.z = 0.f; z.w = 0.f;
    for (int j = idx; j < 36864; j += 16384) ((float4*)D)[j] = z;
    return;
  }
  if (b < 256) {
    int n = b >> 5, pix = (b >> 1) & 15, half = b & 1;
    const float* sp = style + n * 8192 + pix;
    for (int i = threadIdx.x; i < 512; i += 256) s[i] = sp[i * 16];
    __syncthreads();
    int co = half * 256 + threadIdx.x;
    const float4* wr = (const float4*)(dw1_w + co * 512);
    float acc = dw1_b[co];
#pragma unroll 8
    for (int k = 0; k < 128; ++k) {
      float4 wv = wr[k];
      acc += wv.x * s[4*k] + wv.y * s[4*k+1] + wv.z * s[4*k+2] + wv.w * s[4*k+3];
    }
    h2[n * 8192 + pix * 512 + co] = LRELU(acc);
  } else {
    int idx = b - 256; int n = idx >> 1, which = idx & 1;
    for (int ci = threadIdx.x; ci < 512; ci += 256) {
      const float4* r4 = (const float4*)(style + n * 8192 + ci * 16);
      float4 a = r4[0], bb = r4[1], c = r4[2], d = r4[3];
      s[ci] = (a.x+a.y+a.z+a.w + bb.x+bb.y+bb.z+bb.w + c.x+c.y+c.z+c.w + d.x+d.y+d.z+d.w) * (1.f/16.f);
    }
    __syncthreads();
    const float* w  = which ? pb1_w : pk1_w;
    const float* bv = which ? pb1_b : pk1_b;
    float* o = which ? t2 : t1;
    for (int co = threadIdx.x; co < 512; co += 256) {
      const float4* wr = (const float4*)(w + co * 512);
      float acc = bv[co];
#pragma unroll 8
      for (int k = 0; k < 128; ++k) {
        float4 wv = wr[k];
        acc += wv.x * s[4*k] + wv.y * s[4*k+1] + wv.z * s[4*k+2] + wv.w * s[4*k+3];
      }
      o[n * 512 + co] = LRELU(acc);
    }
  }
}

// ---------------- kB: dw2 matmul (on-the-fly im2col) + pk2/pb2 ----------------
__global__ __launch_bounds__(256) void kB(const float* __restrict__ h2,
    const float* __restrict__ dw2_w,
    const float* __restrict__ t1, const float* __restrict__ t2,
    const float* __restrict__ pk2_w, const float* __restrict__ pk2_b,
    const float* __restrict__ pb2_w, const float* __restrict__ pb2_b,
    float* __restrict__ D, float* __restrict__ pk, float* __restrict__ pb) {
  __shared__ float smem[1280];
  int b = blockIdx.x;
  int tid = threadIdx.x;
  if (b < 512) {
    int kc = b & 31; int bt = b >> 5; int bo = bt & 7; int nh = bt >> 3;
    {
      int pix = tid & 15; int ci4 = (tid >> 4) & 3; int nn = tid >> 6;
      const float* src = h2 + (nh * 4 + nn) * 8192 + pix * 512 + kc * 16 + ci4 * 4;
      float4 v = *(const float4*)src;
      float* dst = &smem[(nn * 16 + ci4 * 4) * 20 + pix];
      dst[0]  = v.x;
      dst[20] = v.y;
      dst[40] = v.z;
      dst[60] = v.w;
    }
    __syncthreads();
    int o2 = bo * 256 + tid;
    const float4* wr = (const float4*)(dw2_w + o2 * 2048 + kc * 64);
    float acc[4][9];
#pragma unroll
    for (int nn = 0; nn < 4; ++nn)
#pragma unroll
      for (int p = 0; p < 9; ++p) acc[nn][p] = 0.f;
    for (int ci = 0; ci < 16; ++ci) {
      float4 wv = wr[ci];
#pragma unroll
      for (int nn = 0; nn < 4; ++nn) {
        const float* hrow = &smem[(nn * 16 + ci) * 20];
        float4 a0 = *(const float4*)(hrow + 0);
        float4 a1 = *(const float4*)(hrow + 4);
        float4 a2 = *(const float4*)(hrow + 8);
        float4 a3 = *(const float4*)(hrow + 12);
        float vv[16];
        vv[0]=a0.x; vv[1]=a0.y; vv[2]=a0.z; vv[3]=a0.w;
        vv[4]=a1.x; vv[5]=a1.y; vv[6]=a1.z; vv[7]=a1.w;
        vv[8]=a2.x; vv[9]=a2.y; vv[10]=a2.z; vv[11]=a2.w;
        vv[12]=a3.x; vv[13]=a3.y; vv[14]=a3.z; vv[15]=a3.w;
#pragma unroll
        for (int p = 0; p < 9; ++p) {
          int r = (p / 3) * 4 + (p % 3);
          acc[nn][p] += wv.x * vv[r] + wv.y * vv[r + 1] + wv.z * vv[r + 4] + wv.w * vv[r + 5];
        }
      }
    }
#pragma unroll
    for (int nn = 0; nn < 4; ++nn)
#pragma unroll
      for (int p = 0; p < 9; ++p)
        atomicAdd(&D[((nh * 4 + nn) * 9 + p) * 2048 + o2], acc[nn][p]);
  } else {
    int idx = b - 512;
    int n = idx / 10; int tile = idx % 10;
    bool isPb = tile >= 8;
    float* s = smem;
    const float* src = (isPb ? t2 : t1) + n * 512;
    for (int i = tid; i < 512; i += 256) s[i] = src[i];
    __syncthreads();
    int o = (isPb ? tile - 8 : tile) * 256 + tid;
    const float* w = isPb ? pb2_w : pk2_w;
    float acc = (isPb ? pb2_b : pk2_b)[o];
    const float4* wr = (const float4*)(w + o * 512);
#pragma unroll 8
    for (int k = 0; k < 128; ++k) {
      float4 wv = wr[k];
      acc += wv.x * s[4*k] + wv.y * s[4*k+1] + wv.z * s[4*k+2] + wv.w * s[4*k+3];
    }
    if (isPb) pb[n * 512 + o] = acc; else pk[n * 2048 + o] = acc;
  }
}

// ---------------- kW: weff + pb -> wbuf[n][Q][160] ----------------
__global__ __launch_bounds__(256) void kW(const float* __restrict__ D,
    const float* __restrict__ pk, const float* __restrict__ dw2_b,
    const float* __restrict__ pb, float* __restrict__ wbuf) {
  int idx = blockIdx.x * 256 + threadIdx.x;
  if (idx >= 8 * 128 * 160) return;
  int t = idx % 160; int Qn = idx / 160; int Q = Qn & 127; int n = Qn >> 7;
  if (t >= 144) {
    wbuf[idx] = (t < 148) ? pb[n * 512 + Q * 4 + (t - 144)] : 0.f;
    return;
  }
  int o = t & 3; int u = t >> 2; int kx = u % 3; int v = u / 3;
  int i = v & 3; int ky = v >> 2; int p = ky * 3 + kx;
  const float* Dp  = D + (n * 9 + p) * 2048 + 16 * Q;
  const float* pkp = pk + n * 2048 + 16 * Q + 4 * o;
  const float* bp  = dw2_b + 16 * Q;
  float sum = 0.f;
#pragma unroll
  for (int j = 0; j < 4; ++j) sum += pkp[j] * (Dp[4 * j + i] + bp[4 * j + i]);
  wbuf[idx] = sum;
}

// ---------------- kC v8: no-LDS, 4px/thread, shfl halos, small live set ----------------
// block = (n, Q, 16-row quarter); thread = (r 0..15, e 0..15): 4 o x 4 px
__global__ __launch_bounds__(256, 8) void kC(const float* __restrict__ x,
    const float* __restrict__ wbuf, float* __restrict__ out) {
  int b = blockIdx.x; int rt = b & 3; int Q = (b >> 2) & 127; int n = b >> 9;
  const float* wb = wbuf + (size_t)(n * 128 + Q) * 160;  // block-uniform -> s_load
  const float* base = x + (size_t)(n * 512 + Q * 4) * 4096;
  int e = threadIdx.x & 15;
  int y = rt * 16 + (threadIdx.x >> 4);
  int x0 = 4 * e;
  int ro[3];
#pragma unroll
  for (int ky = 0; ky < 3; ++ky) {
    int ry = y - 1 + ky;
    ry = ry < 0 ? 1 : (ry > 63 ? 62 : ry);
    ro[ky] = ry * 64;
  }
  float acc[4][4];
#pragma unroll
  for (int o = 0; o < 4; ++o) {
    float bv = wb[144 + o];
#pragma unroll
    for (int px = 0; px < 4; ++px) acc[o][px] = bv;
  }
#pragma unroll
  for (int i = 0; i < 4; ++i) {
    const float* ci = base + i * 4096;
#pragma unroll
    for (int ky = 0; ky < 3; ++ky) {
      float4 v0 = *(const float4*)(ci + ro[ky] + x0);
      // halos via width-16 shuffles (lanes with same y)
      float vl = __shfl_up(v0.w, 1, 16);    // lane e-1's x0+3 = x0-1
      float vr = __shfl_down(v0.x, 1, 16);  // lane e+1's x0+4
      if (e == 0)  vl = v0.y;               // x=-1  -> reflect x=1
      if (e == 15) vr = v0.z;               // x=64  -> reflect x=62
      float va0 = vl, va1 = v0.x, va2 = v0.y, va3 = v0.z, va4 = v0.w, va5 = vr;
#pragma unroll
      for (int kx = 0; kx < 3; ++kx) {
        const float* wp = &wb[((ky * 4 + i) * 3 + kx) * 4];
        float w0 = wp[0], w1 = wp[1], w2 = wp[2], w3 = wp[3];
        float xv0 = kx == 0 ? va0 : (kx == 1 ? va1 : va2);
        float xv1 = kx == 0 ? va1 : (kx == 1 ? va2 : va3);
        float xv2 = kx == 0 ? va2 : (kx == 1 ? va3 : va4);
        float xv3 = kx == 0 ? va3 : (kx == 1 ? va4 : va5);
        acc[0][0] += w0 * xv0; acc[0][1] += w0 * xv1; acc[0][2] += w0 * xv2; acc[0][3] += w0 * xv3;
        acc[1][0] += w1 * xv0; acc[1][1] += w1 * xv1; acc[1][2] += w1 * xv2; acc[1][3] += w1 * xv3;
        acc[2][0] += w2 * xv0; acc[2][1] += w2 * xv1; acc[2][2] += w2 * xv2; acc[2][3] += w2 * xv3;
        acc[3][0] += w3 * xv0; acc[3][1] += w3 * xv1; acc[3][2] += w3 * xv2; acc[3][3] += w3 * xv3;
      }
    }
  }
#pragma unroll
  for (int o = 0; o < 4; ++o) {
    float4 st; st.x = acc[o][0]; st.y = acc[o][1]; st.z = acc[o][2]; st.w = acc[o][3];
    *(float4*)&out[(((size_t)(n * 512 + Q * 4 + o)) * 64 + y) * 64 + x0] = st;
  }
}

extern "C" void kernel_launch(void* const* d_in, const int* in_sizes, int n_in,
                              void* d_out, int out_size, void* d_ws, size_t ws_size,
                              hipStream_t stream) {
  const float* style = (const float*)d_in[0];
  const float* pred  = (const float*)d_in[1];
  const float* dw1_w = (const float*)d_in[2];
  const float* dw1_b = (const float*)d_in[3];
  const float* dw2_w = (const float*)d_in[4];
  const float* dw2_b = (const float*)d_in[5];
  const float* pk1_w = (const float*)d_in[6];
  const float* pk1_b = (const float*)d_in[7];
  const float* pk2_w = (const float*)d_in[8];
  const float* pk2_b = (const float*)d_in[9];
  const float* pb1_w = (const float*)d_in[10];
  const float* pb1_b = (const float*)d_in[11];
  const float* pb2_w = (const float*)d_in[12];
  const float* pb2_b = (const float*)d_in[13];
  float* ws = (float*)d_ws;
  float* h2 = ws + H2_OFF;
  float* t1 = ws + T1_OFF;
  float* t2 = ws + T2_OFF;
  float* pk = ws + PK_OFF;
  float* pb = ws + PB_OFF;
  float* D  = ws + D_OFF;
  float* wb = ws + WB_OFF;
  float* out = (float*)d_out;

  kA<<<336, 256, 0, stream>>>(style, dw1_w, dw1_b, pk1_w, pk1_b, pb1_w, pb1_b, h2, t1, t2, D);
  kB<<<592, 256, 0, stream>>>(h2, dw2_w, t1, t2, pk2_w, pk2_b, pb2_w, pb2_b, D, pk, pb);
  kW<<<640, 256, 0, stream>>>(D, pk, dw2_b, pb, wb);
  kC<<<4096, 256, 0, stream>>>(pred, wb, out);
}

// Round 13
// 115.069 us; speedup vs baseline: 2.8128x; 1.6517x over previous
//
#include <hip/hip_runtime.h>

#define LRELU(x) ((x) > 0.f ? (x) : 0.01f * (x))

// ws layout (float offsets)
#define H2_OFF    0          // [8][16][512]
#define T1_OFF    65536      // [8][512]
#define T2_OFF    69632      // [8][512]
#define PK_OFF    73728      // [8][2048]
#define PB_OFF    90112      // [8][512]
#define D_OFF     94208      // [8][9][2048]
#define WB_OFF    241664     // [8][128][160]  (144 weff + 4 pb + 12 pad)

// ---------------- kA: h (1x1 conv + lrelu), pooled stage 1, and D zero-init ----------------
__global__ __launch_bounds__(256) void kA(const float* __restrict__ style,
    const float* __restrict__ dw1_w, const float* __restrict__ dw1_b,
    const float* __restrict__ pk1_w, const float* __restrict__ pk1_b,
    const float* __restrict__ pb1_w, const float* __restrict__ pb1_b,
    float* __restrict__ h2, float* __restrict__ t1, float* __restrict__ t2,
    float* __restrict__ D) {
  int b = blockIdx.x;
  __shared__ float s[512];
  if (b >= 272) {
    int idx = (b - 272) * 256 + threadIdx.x;
    float4 z; z.x = 0.f; z.y = 0.f; z.z = 0.f; z.w = 0.f;
    for (int j = idx; j < 36864; j += 16384) ((float4*)D)[j] = z;
    return;
  }
  if (b < 256) {
    int n = b >> 5, pix = (b >> 1) & 15, half = b & 1;
    const float* sp = style + n * 8192 + pix;
    for (int i = threadIdx.x; i < 512; i += 256) s[i] = sp[i * 16];
    __syncthreads();
    int co = half * 256 + threadIdx.x;
    const float4* wr = (const float4*)(dw1_w + co * 512);
    float acc = dw1_b[co];
#pragma unroll 8
    for (int k = 0; k < 128; ++k) {
      float4 wv = wr[k];
      acc += wv.x * s[4*k] + wv.y * s[4*k+1] + wv.z * s[4*k+2] + wv.w * s[4*k+3];
    }
    h2[n * 8192 + pix * 512 + co] = LRELU(acc);
  } else {
    int idx = b - 256; int n = idx >> 1, which = idx & 1;
    for (int ci = threadIdx.x; ci < 512; ci += 256) {
      const float4* r4 = (const float4*)(style + n * 8192 + ci * 16);
      float4 a = r4[0], bb = r4[1], c = r4[2], d = r4[3];
      s[ci] = (a.x+a.y+a.z+a.w + bb.x+bb.y+bb.z+bb.w + c.x+c.y+c.z+c.w + d.x+d.y+d.z+d.w) * (1.f/16.f);
    }
    __syncthreads();
    const float* w  = which ? pb1_w : pk1_w;
    const float* bv = which ? pb1_b : pk1_b;
    float* o = which ? t2 : t1;
    for (int co = threadIdx.x; co < 512; co += 256) {
      const float4* wr = (const float4*)(w + co * 512);
      float acc = bv[co];
#pragma unroll 8
      for (int k = 0; k < 128; ++k) {
        float4 wv = wr[k];
        acc += wv.x * s[4*k] + wv.y * s[4*k+1] + wv.z * s[4*k+2] + wv.w * s[4*k+3];
      }
      o[n * 512 + co] = LRELU(acc);
    }
  }
}

// ---------------- kB: dw2 matmul (on-the-fly im2col) + pk2/pb2 ----------------
__global__ __launch_bounds__(256) void kB(const float* __restrict__ h2,
    const float* __restrict__ dw2_w,
    const float* __restrict__ t1, const float* __restrict__ t2,
    const float* __restrict__ pk2_w, const float* __restrict__ pk2_b,
    const float* __restrict__ pb2_w, const float* __restrict__ pb2_b,
    float* __restrict__ D, float* __restrict__ pk, float* __restrict__ pb) {
  __shared__ float smem[1280];
  int b = blockIdx.x;
  int tid = threadIdx.x;
  if (b < 512) {
    int kc = b & 31; int bt = b >> 5; int bo = bt & 7; int nh = bt >> 3;
    {
      int pix = tid & 15; int ci4 = (tid >> 4) & 3; int nn = tid >> 6;
      const float* src = h2 + (nh * 4 + nn) * 8192 + pix * 512 + kc * 16 + ci4 * 4;
      float4 v = *(const float4*)src;
      float* dst = &smem[(nn * 16 + ci4 * 4) * 20 + pix];
      dst[0]  = v.x;
      dst[20] = v.y;
      dst[40] = v.z;
      dst[60] = v.w;
    }
    __syncthreads();
    int o2 = bo * 256 + tid;
    const float4* wr = (const float4*)(dw2_w + o2 * 2048 + kc * 64);
    float acc[4][9];
#pragma unroll
    for (int nn = 0; nn < 4; ++nn)
#pragma unroll
      for (int p = 0; p < 9; ++p) acc[nn][p] = 0.f;
    for (int ci = 0; ci < 16; ++ci) {
      float4 wv = wr[ci];
#pragma unroll
      for (int nn = 0; nn < 4; ++nn) {
        const float* hrow = &smem[(nn * 16 + ci) * 20];
        float4 a0 = *(const float4*)(hrow + 0);
        float4 a1 = *(const float4*)(hrow + 4);
        float4 a2 = *(const float4*)(hrow + 8);
        float4 a3 = *(const float4*)(hrow + 12);
        float vv[16];
        vv[0]=a0.x; vv[1]=a0.y; vv[2]=a0.z; vv[3]=a0.w;
        vv[4]=a1.x; vv[5]=a1.y; vv[6]=a1.z; vv[7]=a1.w;
        vv[8]=a2.x; vv[9]=a2.y; vv[10]=a2.z; vv[11]=a2.w;
        vv[12]=a3.x; vv[13]=a3.y; vv[14]=a3.z; vv[15]=a3.w;
#pragma unroll
        for (int p = 0; p < 9; ++p) {
          int r = (p / 3) * 4 + (p % 3);
          acc[nn][p] += wv.x * vv[r] + wv.y * vv[r + 1] + wv.z * vv[r + 4] + wv.w * vv[r + 5];
        }
      }
    }
#pragma unroll
    for (int nn = 0; nn < 4; ++nn)
#pragma unroll
      for (int p = 0; p < 9; ++p)
        atomicAdd(&D[((nh * 4 + nn) * 9 + p) * 2048 + o2], acc[nn][p]);
  } else {
    int idx = b - 512;
    int n = idx / 10; int tile = idx % 10;
    bool isPb = tile >= 8;
    float* s = smem;
    const float* src = (isPb ? t2 : t1) + n * 512;
    for (int i = tid; i < 512; i += 256) s[i] = src[i];
    __syncthreads();
    int o = (isPb ? tile - 8 : tile) * 256 + tid;
    const float* w = isPb ? pb2_w : pk2_w;
    float acc = (isPb ? pb2_b : pk2_b)[o];
    const float4* wr = (const float4*)(w + o * 512);
#pragma unroll 8
    for (int k = 0; k < 128; ++k) {
      float4 wv = wr[k];
      acc += wv.x * s[4*k] + wv.y * s[4*k+1] + wv.z * s[4*k+2] + wv.w * s[4*k+3];
    }
    if (isPb) pb[n * 512 + o] = acc; else pk[n * 2048 + o] = acc;
  }
}

// ---------------- kW: weff + pb -> wbuf[n][Q][160] ----------------
__global__ __launch_bounds__(256) void kW(const float* __restrict__ D,
    const float* __restrict__ pk, const float* __restrict__ dw2_b,
    const float* __restrict__ pb, float* __restrict__ wbuf) {
  int idx = blockIdx.x * 256 + threadIdx.x;
  if (idx >= 8 * 128 * 160) return;
  int t = idx % 160; int Qn = idx / 160; int Q = Qn & 127; int n = Qn >> 7;
  if (t >= 144) {
    wbuf[idx] = (t < 148) ? pb[n * 512 + Q * 4 + (t - 144)] : 0.f;
    return;
  }
  int o = t & 3; int u = t >> 2; int kx = u % 3; int v = u / 3;
  int i = v & 3; int ky = v >> 2; int p = ky * 3 + kx;
  const float* Dp  = D + (n * 9 + p) * 2048 + 16 * Q;
  const float* pkp = pk + n * 2048 + 16 * Q + 4 * o;
  const float* bp  = dw2_b + 16 * Q;
  float sum = 0.f;
#pragma unroll
  for (int j = 0; j < 4; ++j) sum += pkp[j] * (Dp[4 * j + i] + bp[4 * j + i]);
  wbuf[idx] = sum;
}

// ---------------- kC v9: no-LDS, 4px/thread, shfl halos, natural VGPR ----------------
// block = (n, Q, 16-row quarter); thread = (r 0..15, e 0..15): 4 o x 4 px
__global__ __launch_bounds__(256) void kC(const float* __restrict__ x,
    const float* __restrict__ wbuf, float* __restrict__ out) {
  int b = blockIdx.x; int rt = b & 3; int Q = (b >> 2) & 127; int n = b >> 9;
  const float* wb = wbuf + (size_t)(n * 128 + Q) * 160;  // block-uniform -> s_load
  const float* base = x + (size_t)(n * 512 + Q * 4) * 4096;
  int e = threadIdx.x & 15;
  int y = rt * 16 + (threadIdx.x >> 4);
  int x0 = 4 * e;
  int ro[3];
#pragma unroll
  for (int ky = 0; ky < 3; ++ky) {
    int ry = y - 1 + ky;
    ry = ry < 0 ? 1 : (ry > 63 ? 62 : ry);
    ro[ky] = ry * 64;
  }
  float acc[4][4];
#pragma unroll
  for (int o = 0; o < 4; ++o) {
    float bv = wb[144 + o];
#pragma unroll
    for (int px = 0; px < 4; ++px) acc[o][px] = bv;
  }
#pragma unroll
  for (int i = 0; i < 4; ++i) {
    const float* ci = base + i * 4096;
#pragma unroll
    for (int ky = 0; ky < 3; ++ky) {
      float4 v0 = *(const float4*)(ci + ro[ky] + x0);
      // halos via width-16 shuffles (lanes with same y)
      float vl = __shfl_up(v0.w, 1, 16);    // lane e-1's x0+3 = x0-1
      float vr = __shfl_down(v0.x, 1, 16);  // lane e+1's x0+4
      if (e == 0)  vl = v0.y;               // x=-1  -> reflect x=1
      if (e == 15) vr = v0.z;               // x=64  -> reflect x=62
      float va0 = vl, va1 = v0.x, va2 = v0.y, va3 = v0.z, va4 = v0.w, va5 = vr;
#pragma unroll
      for (int kx = 0; kx < 3; ++kx) {
        const float* wp = &wb[((ky * 4 + i) * 3 + kx) * 4];
        float w0 = wp[0], w1 = wp[1], w2 = wp[2], w3 = wp[3];
        float xv0 = kx == 0 ? va0 : (kx == 1 ? va1 : va2);
        float xv1 = kx == 0 ? va1 : (kx == 1 ? va2 : va3);
        float xv2 = kx == 0 ? va2 : (kx == 1 ? va3 : va4);
        float xv3 = kx == 0 ? va3 : (kx == 1 ? va4 : va5);
        acc[0][0] += w0 * xv0; acc[0][1] += w0 * xv1; acc[0][2] += w0 * xv2; acc[0][3] += w0 * xv3;
        acc[1][0] += w1 * xv0; acc[1][1] += w1 * xv1; acc[1][2] += w1 * xv2; acc[1][3] += w1 * xv3;
        acc[2][0] += w2 * xv0; acc[2][1] += w2 * xv1; acc[2][2] += w2 * xv2; acc[2][3] += w2 * xv3;
        acc[3][0] += w3 * xv0; acc[3][1] += w3 * xv1; acc[3][2] += w3 * xv2; acc[3][3] += w3 * xv3;
      }
    }
  }
#pragma unroll
  for (int o = 0; o < 4; ++o) {
    float4 st; st.x = acc[o][0]; st.y = acc[o][1]; st.z = acc[o][2]; st.w = acc[o][3];
    *(float4*)&out[(((size_t)(n * 512 + Q * 4 + o)) * 64 + y) * 64 + x0] = st;
  }
}

extern "C" void kernel_launch(void* const* d_in, const int* in_sizes, int n_in,
                              void* d_out, int out_size, void* d_ws, size_t ws_size,
                              hipStream_t stream) {
  const float* style = (const float*)d_in[0];
  const float* pred  = (const float*)d_in[1];
  const float* dw1_w = (const float*)d_in[2];
  const float* dw1_b = (const float*)d_in[3];
  const float* dw2_w = (const float*)d_in[4];
  const float* dw2_b = (const float*)d_in[5];
  const float* pk1_w = (const float*)d_in[6];
  const float* pk1_b = (const float*)d_in[7];
  const float* pk2_w = (const float*)d_in[8];
  const float* pk2_b = (const float*)d_in[9];
  const float* pb1_w = (const float*)d_in[10];
  const float* pb1_b = (const float*)d_in[11];
  const float* pb2_w = (const float*)d_in[12];
  const float* pb2_b = (const float*)d_in[13];
  float* ws = (float*)d_ws;
  float* h2 = ws + H2_OFF;
  float* t1 = ws + T1_OFF;
  float* t2 = ws + T2_OFF;
  float* pk = ws + PK_OFF;
  float* pb = ws + PB_OFF;
  float* D  = ws + D_OFF;
  float* wb = ws + WB_OFF;
  float* out = (float*)d_out;

  kA<<<336, 256, 0, stream>>>(style, dw1_w, dw1_b, pk1_w, pk1_b, pb1_w, pb1_b, h2, t1, t2, D);
  kB<<<592, 256, 0, stream>>>(h2, dw2_w, t1, t2, pk2_w, pk2_b, pb2_w, pb2_b, D, pk, pb);
  kW<<<640, 256, 0, stream>>>(D, pk, dw2_b, pb, wb);
  kC<<<4096, 256, 0, stream>>>(pred, wb, out);
}

// Round 14
// 86.666 us; speedup vs baseline: 3.7347x; 1.3277x over previous
//
#include <hip/hip_runtime.h>

#define LRELU(x) ((x) > 0.f ? (x) : 0.01f * (x))

// ws layout (float offsets)
#define H2_OFF    0          // [8][16][512]
#define T1_OFF    65536      // [8][512]
#define T2_OFF    69632      // [8][512]
#define PK_OFF    73728      // [8][2048]
#define PB_OFF    90112      // [8][512]
#define D_OFF     94208      // [8][9][2048]
#define WB_OFF    241664     // [8][128][160]  (144 weff + 4 pb + 12 pad)

// ---------------- kA v3: wave-GEMV (lane-split K, shfl reduce) + D zero ----------------
// blocks 0..511:   h[n][pix][co] ; (n, pix, cq): wave handles 32 co of quarter cq
// blocks 512..575: pooled stage1 ; (n, which, cq)
// blocks 576..639: zero D
__global__ __launch_bounds__(256) void kA(const float* __restrict__ style,
    const float* __restrict__ dw1_w, const float* __restrict__ dw1_b,
    const float* __restrict__ pk1_w, const float* __restrict__ pk1_b,
    const float* __restrict__ pb1_w, const float* __restrict__ pb1_b,
    float* __restrict__ h2, float* __restrict__ t1, float* __restrict__ t2,
    float* __restrict__ D) {
  int b = blockIdx.x;
  int tid = threadIdx.x;
  __shared__ float smem[512];
  if (b >= 576) {
    int idx = (b - 576) * 256 + tid;
    float4 z; z.x = 0.f; z.y = 0.f; z.z = 0.f; z.w = 0.f;
    for (int j = idx; j < 36864; j += 16384) ((float4*)D)[j] = z;
    return;
  }
  int wave = tid >> 6, l = tid & 63;
  float sv[8];
  const float* w;
  const float* bv;
  float* outp;
  int cobase;
  bool relu;
  if (b < 512) {
    int n = b >> 6; int pix = (b >> 2) & 15; int cq = b & 3;
    const float* sp = style + n * 8192 + pix;
#pragma unroll
    for (int j = 0; j < 8; ++j) sv[j] = sp[(8 * l + j) * 16];
    w = dw1_w; bv = dw1_b;
    cobase = cq * 128 + wave * 32;
    outp = h2 + n * 8192 + pix * 512;
    relu = true;
  } else {
    int b2 = b - 512;
    int cq = b2 & 3; int which = (b2 >> 2) & 1; int n = b2 >> 3;
    for (int ci = tid; ci < 512; ci += 256) {
      const float4* r4 = (const float4*)(style + n * 8192 + ci * 16);
      float4 a = r4[0], bb = r4[1], c = r4[2], d = r4[3];
      smem[ci] = (a.x+a.y+a.z+a.w + bb.x+bb.y+bb.z+bb.w + c.x+c.y+c.z+c.w + d.x+d.y+d.z+d.w) * (1.f/16.f);
    }
    __syncthreads();
#pragma unroll
    for (int j = 0; j < 8; ++j) sv[j] = smem[8 * l + j];
    w  = which ? pb1_w : pk1_w;
    bv = which ? pb1_b : pk1_b;
    cobase = cq * 128 + wave * 32;
    outp = (which ? t2 : t1) + n * 512;
    relu = true;
  }
  float res = (l < 32) ? bv[cobase + l] : 0.f;
#pragma unroll 8
  for (int j = 0; j < 32; ++j) {
    int co = cobase + j;
    const float4* wr = (const float4*)(w + co * 512 + 8 * l);
    float4 a = wr[0], c = wr[1];
    float v = a.x*sv[0] + a.y*sv[1] + a.z*sv[2] + a.w*sv[3]
            + c.x*sv[4] + c.y*sv[5] + c.z*sv[6] + c.w*sv[7];
    v += __shfl_xor(v, 1);
    v += __shfl_xor(v, 2);
    v += __shfl_xor(v, 4);
    v += __shfl_xor(v, 8);
    v += __shfl_xor(v, 16);
    v += __shfl_xor(v, 32);
    if (l == j) res += v;
  }
  if (l < 32) {
    float o = relu ? LRELU(res) : res;
    outp[cobase + l] = o;
  }
}

// ---------------- kB: dw2 matmul (on-the-fly im2col) + pk2/pb2 ----------------
__global__ __launch_bounds__(256) void kB(const float* __restrict__ h2,
    const float* __restrict__ dw2_w,
    const float* __restrict__ t1, const float* __restrict__ t2,
    const float* __restrict__ pk2_w, const float* __restrict__ pk2_b,
    const float* __restrict__ pb2_w, const float* __restrict__ pb2_b,
    float* __restrict__ D, float* __restrict__ pk, float* __restrict__ pb) {
  __shared__ float smem[1280];
  int b = blockIdx.x;
  int tid = threadIdx.x;
  if (b < 512) {
    int kc = b & 31; int bt = b >> 5; int bo = bt & 7; int nh = bt >> 3;
    {
      int pix = tid & 15; int ci4 = (tid >> 4) & 3; int nn = tid >> 6;
      const float* src = h2 + (nh * 4 + nn) * 8192 + pix * 512 + kc * 16 + ci4 * 4;
      float4 v = *(const float4*)src;
      float* dst = &smem[(nn * 16 + ci4 * 4) * 20 + pix];
      dst[0]  = v.x;
      dst[20] = v.y;
      dst[40] = v.z;
      dst[60] = v.w;
    }
    __syncthreads();
    int o2 = bo * 256 + tid;
    const float4* wr = (const float4*)(dw2_w + o2 * 2048 + kc * 64);
    float acc[4][9];
#pragma unroll
    for (int nn = 0; nn < 4; ++nn)
#pragma unroll
      for (int p = 0; p < 9; ++p) acc[nn][p] = 0.f;
    for (int ci = 0; ci < 16; ++ci) {
      float4 wv = wr[ci];
#pragma unroll
      for (int nn = 0; nn < 4; ++nn) {
        const float* hrow = &smem[(nn * 16 + ci) * 20];
        float4 a0 = *(const float4*)(hrow + 0);
        float4 a1 = *(const float4*)(hrow + 4);
        float4 a2 = *(const float4*)(hrow + 8);
        float4 a3 = *(const float4*)(hrow + 12);
        float vv[16];
        vv[0]=a0.x; vv[1]=a0.y; vv[2]=a0.z; vv[3]=a0.w;
        vv[4]=a1.x; vv[5]=a1.y; vv[6]=a1.z; vv[7]=a1.w;
        vv[8]=a2.x; vv[9]=a2.y; vv[10]=a2.z; vv[11]=a2.w;
        vv[12]=a3.x; vv[13]=a3.y; vv[14]=a3.z; vv[15]=a3.w;
#pragma unroll
        for (int p = 0; p < 9; ++p) {
          int r = (p / 3) * 4 + (p % 3);
          acc[nn][p] += wv.x * vv[r] + wv.y * vv[r + 1] + wv.z * vv[r + 4] + wv.w * vv[r + 5];
        }
      }
    }
#pragma unroll
    for (int nn = 0; nn < 4; ++nn)
#pragma unroll
      for (int p = 0; p < 9; ++p)
        atomicAdd(&D[((nh * 4 + nn) * 9 + p) * 2048 + o2], acc[nn][p]);
  } else {
    int idx = b - 512;
    int n = idx / 10; int tile = idx % 10;
    bool isPb = tile >= 8;
    float* s = smem;
    const float* src = (isPb ? t2 : t1) + n * 512;
    for (int i = tid; i < 512; i += 256) s[i] = src[i];
    __syncthreads();
    int o = (isPb ? tile - 8 : tile) * 256 + tid;
    const float* w = isPb ? pb2_w : pk2_w;
    float acc = (isPb ? pb2_b : pk2_b)[o];
    const float4* wr = (const float4*)(w + o * 512);
#pragma unroll 8
    for (int k = 0; k < 128; ++k) {
      float4 wv = wr[k];
      acc += wv.x * s[4*k] + wv.y * s[4*k+1] + wv.z * s[4*k+2] + wv.w * s[4*k+3];
    }
    if (isPb) pb[n * 512 + o] = acc; else pk[n * 2048 + o] = acc;
  }
}

// ---------------- kW: weff + pb -> wbuf[n][Q][160] ----------------
__global__ __launch_bounds__(256) void kW(const float* __restrict__ D,
    const float* __restrict__ pk, const float* __restrict__ dw2_b,
    const float* __restrict__ pb, float* __restrict__ wbuf) {
  int idx = blockIdx.x * 256 + threadIdx.x;
  if (idx >= 8 * 128 * 160) return;
  int t = idx % 160; int Qn = idx / 160; int Q = Qn & 127; int n = Qn >> 7;
  if (t >= 144) {
    wbuf[idx] = (t < 148) ? pb[n * 512 + Q * 4 + (t - 144)] : 0.f;
    return;
  }
  int o = t & 3; int u = t >> 2; int kx = u % 3; int v = u / 3;
  int i = v & 3; int ky = v >> 2; int p = ky * 3 + kx;
  const float* Dp  = D + (n * 9 + p) * 2048 + 16 * Q;
  const float* pkp = pk + n * 2048 + 16 * Q + 4 * o;
  const float* bp  = dw2_b + 16 * Q;
  float sum = 0.f;
#pragma unroll
  for (int j = 0; j < 4; ++j) sum += pkp[j] * (Dp[4 * j + i] + bp[4 * j + i]);
  wbuf[idx] = sum;
}

// ---------------- kC v9: no-LDS, 4px/thread, shfl halos, natural VGPR ----------------
__global__ __launch_bounds__(256) void kC(const float* __restrict__ x,
    const float* __restrict__ wbuf, float* __restrict__ out) {
  int b = blockIdx.x; int rt = b & 3; int Q = (b >> 2) & 127; int n = b >> 9;
  const float* wb = wbuf + (size_t)(n * 128 + Q) * 160;
  const float* base = x + (size_t)(n * 512 + Q * 4) * 4096;
  int e = threadIdx.x & 15;
  int y = rt * 16 + (threadIdx.x >> 4);
  int x0 = 4 * e;
  int ro[3];
#pragma unroll
  for (int ky = 0; ky < 3; ++ky) {
    int ry = y - 1 + ky;
    ry = ry < 0 ? 1 : (ry > 63 ? 62 : ry);
    ro[ky] = ry * 64;
  }
  float acc[4][4];
#pragma unroll
  for (int o = 0; o < 4; ++o) {
    float bv = wb[144 + o];
#pragma unroll
    for (int px = 0; px < 4; ++px) acc[o][px] = bv;
  }
#pragma unroll
  for (int i = 0; i < 4; ++i) {
    const float* ci = base + i * 4096;
#pragma unroll
    for (int ky = 0; ky < 3; ++ky) {
      float4 v0 = *(const float4*)(ci + ro[ky] + x0);
      float vl = __shfl_up(v0.w, 1, 16);
      float vr = __shfl_down(v0.x, 1, 16);
      if (e == 0)  vl = v0.y;
      if (e == 15) vr = v0.z;
      float va0 = vl, va1 = v0.x, va2 = v0.y, va3 = v0.z, va4 = v0.w, va5 = vr;
#pragma unroll
      for (int kx = 0; kx < 3; ++kx) {
        const float* wp = &wb[((ky * 4 + i) * 3 + kx) * 4];
        float w0 = wp[0], w1 = wp[1], w2 = wp[2], w3 = wp[3];
        float xv0 = kx == 0 ? va0 : (kx == 1 ? va1 : va2);
        float xv1 = kx == 0 ? va1 : (kx == 1 ? va2 : va3);
        float xv2 = kx == 0 ? va2 : (kx == 1 ? va3 : va4);
        float xv3 = kx == 0 ? va3 : (kx == 1 ? va4 : va5);
        acc[0][0] += w0 * xv0; acc[0][1] += w0 * xv1; acc[0][2] += w0 * xv2; acc[0][3] += w0 * xv3;
        acc[1][0] += w1 * xv0; acc[1][1] += w1 * xv1; acc[1][2] += w1 * xv2; acc[1][3] += w1 * xv3;
        acc[2][0] += w2 * xv0; acc[2][1] += w2 * xv1; acc[2][2] += w2 * xv2; acc[2][3] += w2 * xv3;
        acc[3][0] += w3 * xv0; acc[3][1] += w3 * xv1; acc[3][2] += w3 * xv2; acc[3][3] += w3 * xv3;
      }
    }
  }
#pragma unroll
  for (int o = 0; o < 4; ++o) {
    float4 st; st.x = acc[o][0]; st.y = acc[o][1]; st.z = acc[o][2]; st.w = acc[o][3];
    *(float4*)&out[(((size_t)(n * 512 + Q * 4 + o)) * 64 + y) * 64 + x0] = st;
  }
}

extern "C" void kernel_launch(void* const* d_in, const int* in_sizes, int n_in,
                              void* d_out, int out_size, void* d_ws, size_t ws_size,
                              hipStream_t stream) {
  const float* style = (const float*)d_in[0];
  const float* pred  = (const float*)d_in[1];
  const float* dw1_w = (const float*)d_in[2];
  const float* dw1_b = (const float*)d_in[3];
  const float* dw2_w = (const float*)d_in[4];
  const float* dw2_b = (const float*)d_in[5];
  const float* pk1_w = (const float*)d_in[6];
  const float* pk1_b = (const float*)d_in[7];
  const float* pk2_w = (const float*)d_in[8];
  const float* pk2_b = (const float*)d_in[9];
  const float* pb1_w = (const float*)d_in[10];
  const float* pb1_b = (const float*)d_in[11];
  const float* pb2_w = (const float*)d_in[12];
  const float* pb2_b = (const float*)d_in[13];
  float* ws = (float*)d_ws;
  float* h2 = ws + H2_OFF;
  float* t1 = ws + T1_OFF;
  float* t2 = ws + T2_OFF;
  float* pk = ws + PK_OFF;
  float* pb = ws + PB_OFF;
  float* D  = ws + D_OFF;
  float* wb = ws + WB_OFF;
  float* out = (float*)d_out;

  kA<<<640, 256, 0, stream>>>(style, dw1_w, dw1_b, pk1_w, pk1_b, pb1_w, pb1_b, h2, t1, t2, D);
  kB<<<592, 256, 0, stream>>>(h2, dw2_w, t1, t2, pk2_w, pk2_b, pb2_w, pb2_b, D, pk, pb);
  kW<<<640, 256, 0, stream>>>(D, pk, dw2_b, pb, wb);
  kC<<<4096, 256, 0, stream>>>(pred, wb, out);
}